// Round 10
// baseline (101.042 us; speedup 1.0000x reference)
//
#include <hip/hip_runtime.h>
#include <hip/hip_fp16.h>

#define N_POST 50000
#define N_IN   17400
#define NNZ_E  1000000
#define T_DIM  64
#define R_DIM  5
#define NT_DIM 10

#define BROWS  256                                  // rows per bucket
#define NBUCK  ((N_POST + BROWS - 1) / BROWS)       // 196
#define CAP1   6144                                 // bucket capacity (mean 5102, +14 sigma)
#define PADCAP 1024                                 // pad allowance per bucket (>256*3)
#define CAPR   (CAP1 + PADCAP)                      // padded rec stride per bucket
#define EPB    2048                                 // edges per split block
#define NBLK1  ((NNZ_E + EPB - 1) / EPB)            // 489

#define TRANS_BLOCKS ((N_IN * T_DIM + 255) / 256)   // 4350

static __device__ __forceinline__ unsigned pack2h(float a, float b) {
    __half2 h = __floats2half2_rn(a, b);
    return *reinterpret_cast<unsigned*>(&h);
}
static __device__ __forceinline__ float2 uph2(unsigned u) {
    __half2 h;
    *reinterpret_cast<unsigned*>(&h) = u;
    return __half22float2(h);
}

// ---- transpose x -> xT (fp16) ----
__global__ __launch_bounds__(256) void k_trans(const float* __restrict__ x,
                                               __half* __restrict__ xT) {
    int tid = blockIdx.x * 256 + threadIdx.x;
    if (tid < N_IN * T_DIM) {
        int col = tid >> 6, t = tid & 63;
        xT[tid] = __float2half(x[t * N_IN + col]);
    }
}

// ---- pass 1: tiny-LDS bucket binning, fixed-stride buckets, direct stores ----
// rec1 record: x = col(15b) | sid<<15 (4b) | row_low<<19 (8b) ; y = weight bits
__global__ __launch_bounds__(256) void k_split(const int2* __restrict__ idx2,
                                               const float* __restrict__ iw,
                                               const int* __restrict__ sid,
                                               int* __restrict__ gcur,
                                               uint2* __restrict__ rec1) {
    __shared__ int lhist[NBUCK];
    __shared__ int lbase[NBUCK];
    int t = threadIdx.x;
    for (int i = t; i < NBUCK; i += 256) lhist[i] = 0;
    __syncthreads();
    int base = blockIdx.x * EPB;
    int n = min(EPB, NNZ_E - base);
    for (int i = t; i < n; i += 256)
        atomicAdd(&lhist[(unsigned)idx2[base + i].x >> 8], 1);
    __syncthreads();
    for (int i = t; i < NBUCK; i += 256) {
        int v = lhist[i];
        lbase[i] = v ? atomicAdd(&gcur[i], v) : 0;
        lhist[i] = 0;                     // reuse as running cursor
    }
    __syncthreads();
    for (int i = t; i < n; i += 256) {
        int2 rc = idx2[base + i];
        unsigned b = (unsigned)rc.x >> 8;
        int pos = lbase[b] + atomicAdd(&lhist[b], 1);
        unsigned x = (unsigned)rc.y | ((unsigned)sid[base + i] << 15)
                   | ((unsigned)(rc.x & 255) << 19);
        rec1[b * CAP1 + pos] = make_uint2(x, __float_as_uint(iw[base + i]));
    }
}

// ---- pass 2: per-bucket fine sort by row; 16B fp16 pre-scaled records,
//      row lists PADDED to multiples of 4; col stored <<7 (byte offset) ----
__global__ __launch_bounds__(256) void k_fine(const uint2* __restrict__ rec1,
                                              const int* __restrict__ gcur,
                                              const float* __restrict__ S,
                                              uint4* __restrict__ rec,
                                              int* __restrict__ rstart,
                                              int* __restrict__ plen) {
    __shared__ int lhist[BROWS];
    __shared__ int lsc[BROWS];
    __shared__ int lcur[BROWS];
    __shared__ float s_S[NT_DIM * R_DIM];
    int t = threadIdx.x;
    if (t < NT_DIM * R_DIM) s_S[t] = S[t];
    int b = blockIdx.x;
    int s0 = b * CAP1;
    int s1 = s0 + gcur[b];
    int pbase = b * CAPR;
    lhist[t] = 0;
    __syncthreads();
    for (int i = s0 + t; i < s1; i += 256)
        atomicAdd(&lhist[(rec1[i].x >> 19) & 255], 1);
    __syncthreads();
    int v = lhist[t];
    int vp = (v + 3) & ~3;
    lsc[t] = vp;
    __syncthreads();
    for (int off = 1; off < 256; off <<= 1) {
        int u = (t >= off) ? lsc[t - off] : 0;
        __syncthreads();
        lsc[t] += u;
        __syncthreads();
    }
    int exclp = lsc[t] - vp;
    int p = b * BROWS + t;
    if (p < N_POST) { rstart[p] = pbase + exclp; plen[p] = vp; }
    lcur[t] = exclp;
    __syncthreads();
    for (int i = s0 + t; i < s1; i += 256) {
        uint2 rc = rec1[i];
        int r = (rc.x >> 19) & 255;
        int pos = atomicAdd(&lcur[r], 1);
        unsigned col = rc.x & 0x7FFF;
        const float* f = &s_S[((rc.x >> 15) & 0xF) * R_DIM];
        float w = __uint_as_float(rc.y);
        uint4 r4;
        r4.x = col << 7;                 // byte offset into fp16 xT
        r4.y = pack2h(w * f[0], w * f[1]);
        r4.z = pack2h(w * f[2], w * f[3]);
        r4.w = pack2h(w * f[4], 0.f);
        rec[pbase + pos] = r4;
    }
    for (int u = v; u < vp; ++u)
        rec[pbase + exclp + u] = make_uint4(0, 0, 0, 0);
}

// gather: byte-offset addressing (record holds col*128)
#define GX(A) (*(const __half*)(xb + ((A).x + lane2)))

#define FMA5(A, xh, c0, c1, c2, c3, c4)                  \
    do {                                                 \
        float xv_ = __half2float(xh);                    \
        float2 f01_ = uph2((A).y);                       \
        float2 f23_ = uph2((A).z);                       \
        float2 f4_  = uph2((A).w);                       \
        c0 = fmaf(xv_, f01_.x, c0);                      \
        c1 = fmaf(xv_, f01_.y, c1);                      \
        c2 = fmaf(xv_, f23_.x, c2);                      \
        c3 = fmaf(xv_, f23_.y, c3);                      \
        c4 = fmaf(xv_, f4_.x,  c4);                      \
    } while (0)

#define LOADG(P, J, R0, R1, R2, R3)                      \
    do { const uint4* q_ = (P) + ((J) << 2);             \
         R0 = q_[0]; R1 = q_[1]; R2 = q_[2]; R3 = q_[3]; } while (0)
#define GATH4(R0, R1, R2, R3, X0, X1, X2, X3)            \
    do { X0 = GX(R0); X1 = GX(R1); X2 = GX(R2); X3 = GX(R3); } while (0)
#define FMAG(R0, R1, R2, R3, X0, X1, X2, X3, c0, c1, c2, c3, c4) \
    do { FMA5(R0, X0, c0, c1, c2, c3, c4);               \
         FMA5(R1, X1, c0, c1, c2, c3, c4);               \
         FMA5(R2, X2, c0, c1, c2, c3, c4);               \
         FMA5(R3, X3, c0, c1, c2, c3, c4); } while (0)

// ---- phase2: 16 rows/block; 2 independent row-chains per wave, each with a
//      3-stage pipeline: load rec grp i+2 || gather grp i+1 || FMA grp i ----
__global__ __launch_bounds__(256) void k_phase2(
        const __half* __restrict__ xT, const int* __restrict__ rstart,
        const int* __restrict__ plen, const uint4* __restrict__ rec,
        float* __restrict__ out) {
    __shared__ float o_lds[T_DIM * 81];
    const char* xb = (const char*)xT;
    int tid = threadIdx.x;
    int wave = tid >> 6, lane = tid & 63;
    int lane2 = lane * 2;
    #pragma unroll
    for (int h = 0; h < 2; ++h) {
        int pa = blockIdx.x * 16 + wave * 4 + h * 2;
        int ia = __builtin_amdgcn_readfirstlane(rstart[pa]);
        int ga = __builtin_amdgcn_readfirstlane(plen[pa]) >> 2;
        int ib = __builtin_amdgcn_readfirstlane(rstart[pa + 1]);
        int gb = __builtin_amdgcn_readfirstlane(plen[pa + 1]) >> 2;
        const uint4* ra = rec + ia;
        const uint4* rb = rec + ib;
        float aa0 = 0.f, aa1 = 0.f, aa2 = 0.f, aa3 = 0.f, aa4 = 0.f;
        float ab0 = 0.f, ab1 = 0.f, ab2 = 0.f, ab3 = 0.f, ab4 = 0.f;
        uint4 A0, A1, A2, A3, D0, D1, D2, D3;
        uint4 B0, B1, B2, B3, E0, E1, E2, E3;
        __half xa0, xa1, xa2, xa3, xb0, xb1, xb2, xb3;
        if (ga) {
            LOADG(ra, 0, A0, A1, A2, A3);
            GATH4(A0, A1, A2, A3, xa0, xa1, xa2, xa3);
            if (ga >= 2) LOADG(ra, 1, D0, D1, D2, D3);
        }
        if (gb) {
            LOADG(rb, 0, B0, B1, B2, B3);
            GATH4(B0, B1, B2, B3, xb0, xb1, xb2, xb3);
            if (gb >= 2) LOADG(rb, 1, E0, E1, E2, E3);
        }
        int it_a = 0, it_b = 0;
        while (it_a + 2 < ga && it_b + 2 < gb) {      // both chains in main stage
            uint4 N0, N1, N2, N3, M0, M1, M2, M3;
            LOADG(ra, it_a + 2, N0, N1, N2, N3);
            LOADG(rb, it_b + 2, M0, M1, M2, M3);
            __half ya0, ya1, ya2, ya3, yb0, yb1, yb2, yb3;
            GATH4(D0, D1, D2, D3, ya0, ya1, ya2, ya3);
            GATH4(E0, E1, E2, E3, yb0, yb1, yb2, yb3);
            FMAG(A0, A1, A2, A3, xa0, xa1, xa2, xa3, aa0, aa1, aa2, aa3, aa4);
            FMAG(B0, B1, B2, B3, xb0, xb1, xb2, xb3, ab0, ab1, ab2, ab3, ab4);
            A0 = D0; A1 = D1; A2 = D2; A3 = D3;
            xa0 = ya0; xa1 = ya1; xa2 = ya2; xa3 = ya3;
            D0 = N0; D1 = N1; D2 = N2; D3 = N3;
            B0 = E0; B1 = E1; B2 = E2; B3 = E3;
            xb0 = yb0; xb1 = yb1; xb2 = yb2; xb3 = yb3;
            E0 = M0; E1 = M1; E2 = M2; E3 = M3;
            ++it_a; ++it_b;
        }
        while (it_a + 2 < ga) {                       // drain chain A main stage
            uint4 N0, N1, N2, N3;
            LOADG(ra, it_a + 2, N0, N1, N2, N3);
            __half ya0, ya1, ya2, ya3;
            GATH4(D0, D1, D2, D3, ya0, ya1, ya2, ya3);
            FMAG(A0, A1, A2, A3, xa0, xa1, xa2, xa3, aa0, aa1, aa2, aa3, aa4);
            A0 = D0; A1 = D1; A2 = D2; A3 = D3;
            xa0 = ya0; xa1 = ya1; xa2 = ya2; xa3 = ya3;
            D0 = N0; D1 = N1; D2 = N2; D3 = N3;
            ++it_a;
        }
        while (it_b + 2 < gb) {                       // drain chain B main stage
            uint4 M0, M1, M2, M3;
            LOADG(rb, it_b + 2, M0, M1, M2, M3);
            __half yb0, yb1, yb2, yb3;
            GATH4(E0, E1, E2, E3, yb0, yb1, yb2, yb3);
            FMAG(B0, B1, B2, B3, xb0, xb1, xb2, xb3, ab0, ab1, ab2, ab3, ab4);
            B0 = E0; B1 = E1; B2 = E2; B3 = E3;
            xb0 = yb0; xb1 = yb1; xb2 = yb2; xb3 = yb3;
            E0 = M0; E1 = M1; E2 = M2; E3 = M3;
            ++it_b;
        }
        if (ga >= 2) {                                // chain A penultimate
            __half ya0, ya1, ya2, ya3;
            GATH4(D0, D1, D2, D3, ya0, ya1, ya2, ya3);
            FMAG(A0, A1, A2, A3, xa0, xa1, xa2, xa3, aa0, aa1, aa2, aa3, aa4);
            A0 = D0; A1 = D1; A2 = D2; A3 = D3;
            xa0 = ya0; xa1 = ya1; xa2 = ya2; xa3 = ya3;
        }
        if (gb >= 2) {                                // chain B penultimate
            __half yb0, yb1, yb2, yb3;
            GATH4(E0, E1, E2, E3, yb0, yb1, yb2, yb3);
            FMAG(B0, B1, B2, B3, xb0, xb1, xb2, xb3, ab0, ab1, ab2, ab3, ab4);
            B0 = E0; B1 = E1; B2 = E2; B3 = E3;
            xb0 = yb0; xb1 = yb1; xb2 = yb2; xb3 = yb3;
        }
        if (ga) FMAG(A0, A1, A2, A3, xa0, xa1, xa2, xa3, aa0, aa1, aa2, aa3, aa4);
        if (gb) FMAG(B0, B1, B2, B3, xb0, xb1, xb2, xb3, ab0, ab1, ab2, ab3, ab4);
        float* da = &o_lds[lane * 81 + (wave * 4 + h * 2) * 5];
        da[0] = aa0; da[1] = aa1; da[2] = aa2; da[3] = aa3; da[4] = aa4;
        float* db = &o_lds[lane * 81 + (wave * 4 + h * 2 + 1) * 5];
        db[0] = ab0; db[1] = ab1; db[2] = ab2; db[3] = ab3; db[4] = ab4;
    }
    __syncthreads();
    int base5 = blockIdx.x * 80;
    for (int i2 = tid; i2 < T_DIM * 80; i2 += 256) {
        int t = i2 / 80;
        int j = i2 - t * 80;
        out[(size_t)t * (N_POST * R_DIM) + base5 + j] = o_lds[t * 81 + j];
    }
}

extern "C" void kernel_launch(void* const* d_in, const int* in_sizes, int n_in,
                              void* d_out, int out_size, void* d_ws, size_t ws_size,
                              hipStream_t stream) {
    const float* inp  = (const float*)d_in[0];
    const int2*  idx2 = (const int2*)d_in[1];
    const float* iw   = (const float*)d_in[2];
    const float* S    = (const float*)d_in[3];
    const int*   sid  = (const int*)d_in[4];
    float* out = (float*)d_out;

    char* ws = (char*)d_ws;
    size_t off = 0;
    auto alloc = [&](size_t bytes) -> void* {
        void* p = ws + off;
        off += (bytes + 255) & ~(size_t)255;
        return p;
    };
    __half* xT       = (__half*)alloc((size_t)N_IN * T_DIM * 2);
    int*   gcur      = (int*)alloc((size_t)NBUCK * 4);
    int*   rstart    = (int*)alloc((size_t)N_POST * 4);
    int*   plen      = (int*)alloc((size_t)N_POST * 4);
    uint2* rec1      = (uint2*)alloc((size_t)NBUCK * CAP1 * 8);
    uint4* rec       = (uint4*)alloc((size_t)NBUCK * CAPR * 16);

    hipMemsetAsync(gcur, 0, NBUCK * 4, stream);
    k_trans<<<TRANS_BLOCKS, 256, 0, stream>>>(inp, xT);
    k_split<<<NBLK1, 256, 0, stream>>>(idx2, iw, sid, gcur, rec1);
    k_fine<<<NBUCK, 256, 0, stream>>>(rec1, gcur, S, rec, rstart, plen);
    k_phase2<<<N_POST / 16, 256, 0, stream>>>(xT, rstart, plen, rec, out);
}

// Round 11
// 98.317 us; speedup vs baseline: 1.0277x; 1.0277x over previous
//
#include <hip/hip_runtime.h>
#include <hip/hip_fp16.h>

#define N_POST 50000
#define N_IN   17400
#define NNZ_E  1000000
#define T_DIM  64
#define R_DIM  5
#define NT_DIM 10

#define BROWS  256                                  // rows per bucket
#define NBUCK  ((N_POST + BROWS - 1) / BROWS)       // 196
#define CAP1   6144                                 // bucket capacity (mean 5102)
#define PADCAP 1024                                 // pad allowance per bucket (>256*3)
#define CAPR   (CAP1 + PADCAP)                      // padded rec stride per bucket
#define EPB    2048                                 // edges per split block
#define NBLK1  ((NNZ_E + EPB - 1) / EPB)            // 489

#define TRANS_BLOCKS ((N_IN * T_DIM + 255) / 256)   // 4350

static __device__ __forceinline__ unsigned pack2h(float a, float b) {
    __half2 h = __floats2half2_rn(a, b);
    return *reinterpret_cast<unsigned*>(&h);
}
static __device__ __forceinline__ float2 uph2(unsigned u) {
    __half2 h;
    *reinterpret_cast<unsigned*>(&h) = u;
    return __half22float2(h);
}

// ---- fused: transpose x -> xT (fp16)  AND  bucket binning (fixed-stride) ----
// rec1 record: x = col(15b) | sid<<15 (4b) | row_low<<19 (8b) ; y = weight bits
__global__ __launch_bounds__(256) void k_fused(const float* __restrict__ x,
                                               __half* __restrict__ xT,
                                               const int2* __restrict__ idx2,
                                               const float* __restrict__ iw,
                                               const int* __restrict__ sid,
                                               int* __restrict__ gcur,
                                               uint2* __restrict__ rec1) {
    int b = blockIdx.x;
    if (b < TRANS_BLOCKS) {
        int tid = b * 256 + threadIdx.x;
        if (tid < N_IN * T_DIM) {
            int col = tid >> 6, t = tid & 63;
            xT[tid] = __float2half(x[t * N_IN + col]);
        }
        return;
    }
    __shared__ int lhist[NBUCK];
    __shared__ int lbase[NBUCK];
    int t = threadIdx.x;
    for (int i = t; i < NBUCK; i += 256) lhist[i] = 0;
    __syncthreads();
    int base = (b - TRANS_BLOCKS) * EPB;
    int n = min(EPB, NNZ_E - base);
    for (int i = t; i < n; i += 256)
        atomicAdd(&lhist[(unsigned)idx2[base + i].x >> 8], 1);
    __syncthreads();
    for (int i = t; i < NBUCK; i += 256) {
        int v = lhist[i];
        lbase[i] = v ? atomicAdd(&gcur[i], v) : 0;
        lhist[i] = 0;                     // reuse as running cursor
    }
    __syncthreads();
    for (int i = t; i < n; i += 256) {
        int2 rc = idx2[base + i];
        unsigned bk = (unsigned)rc.x >> 8;
        int pos = lbase[bk] + atomicAdd(&lhist[bk], 1);
        unsigned xx = (unsigned)rc.y | ((unsigned)sid[base + i] << 15)
                    | ((unsigned)(rc.x & 255) << 19);
        rec1[bk * CAP1 + pos] = make_uint2(xx, __float_as_uint(iw[base + i]));
    }
}

// ---- pass 2: per-bucket fine sort by row; 16B fp16 pre-scaled records,
//      row lists PADDED to multiples of 4; col stored <<7 (byte offset) ----
__global__ __launch_bounds__(256) void k_fine(const uint2* __restrict__ rec1,
                                              const int* __restrict__ gcur,
                                              const float* __restrict__ S,
                                              uint4* __restrict__ rec,
                                              int* __restrict__ rstart,
                                              int* __restrict__ plen) {
    __shared__ int lhist[BROWS];
    __shared__ int lsc[BROWS];
    __shared__ int lcur[BROWS];
    __shared__ float s_S[NT_DIM * R_DIM];
    int t = threadIdx.x;
    if (t < NT_DIM * R_DIM) s_S[t] = S[t];
    int b = blockIdx.x;
    int s0 = b * CAP1;
    int s1 = s0 + gcur[b];
    int pbase = b * CAPR;
    lhist[t] = 0;
    __syncthreads();
    for (int i = s0 + t; i < s1; i += 256)
        atomicAdd(&lhist[(rec1[i].x >> 19) & 255], 1);
    __syncthreads();
    int v = lhist[t];
    int vp = (v + 3) & ~3;
    lsc[t] = vp;
    __syncthreads();
    for (int off = 1; off < 256; off <<= 1) {
        int u = (t >= off) ? lsc[t - off] : 0;
        __syncthreads();
        lsc[t] += u;
        __syncthreads();
    }
    int exclp = lsc[t] - vp;
    int p = b * BROWS + t;
    if (p < N_POST) { rstart[p] = pbase + exclp; plen[p] = vp; }
    lcur[t] = exclp;
    __syncthreads();
    for (int i = s0 + t; i < s1; i += 256) {
        uint2 rc = rec1[i];
        int r = (rc.x >> 19) & 255;
        int pos = atomicAdd(&lcur[r], 1);
        unsigned col = rc.x & 0x7FFF;
        const float* f = &s_S[((rc.x >> 15) & 0xF) * R_DIM];
        float w = __uint_as_float(rc.y);
        uint4 r4;
        r4.x = col << 7;                 // byte offset into fp16 xT
        r4.y = pack2h(w * f[0], w * f[1]);
        r4.z = pack2h(w * f[2], w * f[3]);
        r4.w = pack2h(w * f[4], 0.f);
        rec[pbase + pos] = r4;
    }
    for (int u = v; u < vp; ++u)
        rec[pbase + exclp + u] = make_uint4(0, 0, 0, 0);
}

// FMA of one record into the 10 accumulators (2 t-values x 5 r)
#define FMAREC(Rk, Xk)                                                    \
    do {                                                                  \
        __half2 xh_ = __builtin_bit_cast(__half2, (Xk));                  \
        float xe_ = __half2float(xh_.x), xo_ = __half2float(xh_.y);       \
        float2 w01_ = uph2((Rk).y);                                       \
        float2 w23_ = uph2((Rk).z);                                       \
        float2 w4_  = uph2((Rk).w);                                       \
        a0e = fmaf(xe_, w01_.x, a0e); a0o = fmaf(xo_, w01_.x, a0o);       \
        a1e = fmaf(xe_, w01_.y, a1e); a1o = fmaf(xo_, w01_.y, a1o);       \
        a2e = fmaf(xe_, w23_.x, a2e); a2o = fmaf(xo_, w23_.x, a2o);       \
        a3e = fmaf(xe_, w23_.y, a3e); a3o = fmaf(xo_, w23_.y, a3o);       \
        a4e = fmaf(xe_, w4_.x,  a4e); a4o = fmaf(xo_, w4_.x,  a4o);       \
    } while (0)

// ---- phase2: 16 rows/block; half-wave per row (lane halves = row pair);
//      each lane covers 2 time steps (half2 gather); depth-2 group pipeline ----
__global__ __launch_bounds__(256, 4) void k_phase2(
        const __half* __restrict__ xT, const int* __restrict__ rstart,
        const int* __restrict__ plen, const uint4* __restrict__ rec,
        float* __restrict__ out) {
    __shared__ float o_lds[T_DIM * 81];
    const char* xb = (const char*)xT;
    int tid = threadIdx.x;
    int wave = tid >> 6, lane = tid & 63;
    int half = lane >> 5;
    int lane4 = (lane & 31) * 4;          // byte offset of my half2 within a col row
    #pragma unroll
    for (int h = 0; h < 2; ++h) {
        int pa = blockIdx.x * 16 + wave * 4 + h * 2;
        int myrow = pa + half;
        int ih = rstart[myrow];
        int ng = plen[myrow] >> 2;        // my row's group count
        int na = plen[pa], nb = plen[pa + 1];
        int ngmax = __builtin_amdgcn_readfirstlane((na > nb ? na : nb) >> 2);
        const uint4* rp = rec + ih;
        float a0e = 0.f, a0o = 0.f, a1e = 0.f, a1o = 0.f, a2e = 0.f;
        float a2o = 0.f, a3e = 0.f, a3o = 0.f, a4e = 0.f, a4o = 0.f;
        uint4 R0, R1, R2, R3;
        unsigned X0, X1, X2, X3;
        if (0 < ng) {
            R0 = rp[0]; R1 = rp[1]; R2 = rp[2]; R3 = rp[3];
            X0 = *(const unsigned*)(xb + (R0.x + lane4));
            X1 = *(const unsigned*)(xb + (R1.x + lane4));
            X2 = *(const unsigned*)(xb + (R2.x + lane4));
            X3 = *(const unsigned*)(xb + (R3.x + lane4));
        } else {
            R0 = R1 = R2 = R3 = make_uint4(0, 0, 0, 0);
            X0 = X1 = X2 = X3 = 0;
        }
        for (int g = 1; g < ngmax; ++g) {
            uint4 S0, S1, S2, S3;
            unsigned Y0, Y1, Y2, Y3;
            if (g < ng) {
                const uint4* q = rp + (g << 2);
                S0 = q[0]; S1 = q[1]; S2 = q[2]; S3 = q[3];
                Y0 = *(const unsigned*)(xb + (S0.x + lane4));
                Y1 = *(const unsigned*)(xb + (S1.x + lane4));
                Y2 = *(const unsigned*)(xb + (S2.x + lane4));
                Y3 = *(const unsigned*)(xb + (S3.x + lane4));
            } else {
                S0 = S1 = S2 = S3 = make_uint4(0, 0, 0, 0);
                Y0 = Y1 = Y2 = Y3 = 0;
            }
            FMAREC(R0, X0); FMAREC(R1, X1); FMAREC(R2, X2); FMAREC(R3, X3);
            R0 = S0; R1 = S1; R2 = S2; R3 = S3;
            X0 = Y0; X1 = Y1; X2 = Y2; X3 = Y3;
        }
        if (ngmax > 0) {
            FMAREC(R0, X0); FMAREC(R1, X1); FMAREC(R2, X2); FMAREC(R3, X3);
        }
        int rowl = wave * 4 + h * 2 + half;
        int t0 = (lane & 31) * 2;
        float* d0 = &o_lds[t0 * 81 + rowl * 5];
        d0[0] = a0e; d0[1] = a1e; d0[2] = a2e; d0[3] = a3e; d0[4] = a4e;
        float* d1 = &o_lds[(t0 + 1) * 81 + rowl * 5];
        d1[0] = a0o; d1[1] = a1o; d1[2] = a2o; d1[3] = a3o; d1[4] = a4o;
    }
    __syncthreads();
    int base5 = blockIdx.x * 80;
    for (int i2 = tid; i2 < T_DIM * 80; i2 += 256) {
        int t = i2 / 80;
        int j = i2 - t * 80;
        out[(size_t)t * (N_POST * R_DIM) + base5 + j] = o_lds[t * 81 + j];
    }
}

extern "C" void kernel_launch(void* const* d_in, const int* in_sizes, int n_in,
                              void* d_out, int out_size, void* d_ws, size_t ws_size,
                              hipStream_t stream) {
    const float* inp  = (const float*)d_in[0];
    const int2*  idx2 = (const int2*)d_in[1];
    const float* iw   = (const float*)d_in[2];
    const float* S    = (const float*)d_in[3];
    const int*   sid  = (const int*)d_in[4];
    float* out = (float*)d_out;

    char* ws = (char*)d_ws;
    size_t off = 0;
    auto alloc = [&](size_t bytes) -> void* {
        void* p = ws + off;
        off += (bytes + 255) & ~(size_t)255;
        return p;
    };
    __half* xT       = (__half*)alloc((size_t)N_IN * T_DIM * 2);
    int*   gcur      = (int*)alloc((size_t)NBUCK * 4);
    int*   rstart    = (int*)alloc((size_t)N_POST * 4);
    int*   plen      = (int*)alloc((size_t)N_POST * 4);
    uint2* rec1      = (uint2*)alloc((size_t)NBUCK * CAP1 * 8);
    uint4* rec       = (uint4*)alloc((size_t)NBUCK * CAPR * 16);

    hipMemsetAsync(gcur, 0, NBUCK * 4, stream);
    k_fused<<<TRANS_BLOCKS + NBLK1, 256, 0, stream>>>(inp, xT, idx2, iw, sid, gcur, rec1);
    k_fine<<<NBUCK, 256, 0, stream>>>(rec1, gcur, S, rec, rstart, plen);
    k_phase2<<<N_POST / 16, 256, 0, stream>>>(xT, rstart, plen, rec, out);
}

// Round 12
// 78.608 us; speedup vs baseline: 1.2854x; 1.2507x over previous
//
#include <hip/hip_runtime.h>
#include <hip/hip_fp16.h>

#define N_POST 50000
#define N_IN   17400
#define NNZ_E  1000000
#define T_DIM  64
#define R_DIM  5
#define NT_DIM 10

#define BROWS  256                                  // rows per bucket
#define NBUCK  ((N_POST + BROWS - 1) / BROWS)       // 196
#define EPB    4096                                 // edges per split block
#define NBLK1  ((NNZ_E + EPB - 1) / EPB)            // 245
#define CAP    64                                   // records per (block,bucket) cell
#define FCAP   5632                                 // max records per bucket (mean 5102)
#define CAPR   7168                                 // padded rec stride per bucket
#define CTILES ((N_IN + 63) / 64)                   // 272

static __device__ __forceinline__ unsigned pack2h(float a, float b) {
    __half2 h = __floats2half2_rn(a, b);
    return *reinterpret_cast<unsigned*>(&h);
}
static __device__ __forceinline__ float2 uph2(unsigned u) {
    __half2 h;
    *reinterpret_cast<unsigned*>(&h) = u;
    return __half22float2(h);
}

// ---- LDS-tile transpose: x (64 x 17400) -> xT fp16 (17400 x 64), coalesced both sides ----
__global__ __launch_bounds__(256) void k_trans(const float* __restrict__ x,
                                               __half* __restrict__ xT) {
    __shared__ float tile[64][65];
    int c0 = blockIdx.x * 64;
    int tid = threadIdx.x;
    int l = tid & 63, w = tid >> 6;
    #pragma unroll
    for (int i = 0; i < 16; ++i) {
        int t = i * 4 + w;
        int c = c0 + l;
        tile[l][t] = (c < N_IN) ? x[t * N_IN + c] : 0.f;
    }
    __syncthreads();
    #pragma unroll
    for (int i = 0; i < 16; ++i) {
        int cc = i * 4 + w;
        int c = c0 + cc;
        if (c < N_IN) xT[c * 64 + l] = __float2half(tile[cc][l]);
    }
}

// ---- single-pass bucket binning into fixed-capacity cells; ONE LDS atomic/edge ----
// rec1 record: x = col(15b) | sid<<15 (4b) | row_low<<19 (8b) ; y = weight bits
__global__ __launch_bounds__(256) void k_split(const int2* __restrict__ idx2,
                                               const float* __restrict__ iw,
                                               const int* __restrict__ sid,
                                               unsigned short* __restrict__ cnt,
                                               uint2* __restrict__ rec1) {
    __shared__ int lcur[NBUCK];
    int t = threadIdx.x;
    for (int i = t; i < NBUCK; i += 256) lcur[i] = 0;
    __syncthreads();
    int blk = blockIdx.x;
    int base = blk * EPB;
    int n = min(EPB, NNZ_E - base);
    for (int i = t; i < n; i += 256) {
        int2 rc = idx2[base + i];
        unsigned bk = (unsigned)rc.x >> 8;
        int pos = atomicAdd(&lcur[bk], 1);
        unsigned xx = (unsigned)rc.y | ((unsigned)sid[base + i] << 15)
                    | ((unsigned)(rc.x & 255) << 19);
        rec1[(bk * NBLK1 + blk) * CAP + pos] =
            make_uint2(xx, __float_as_uint(iw[base + i]));
    }
    __syncthreads();
    for (int i = t; i < NBUCK; i += 256)
        cnt[i * NBLK1 + blk] = (unsigned short)lcur[i];
}

// ---- per-bucket: compact cells into LDS, row-hist, scan, emit padded fp16 records ----
// rec (uint4): { col<<7, half2(wf0,wf1), half2(wf2,wf3), half2(wf4,0) }
__global__ __launch_bounds__(512) void k_fine(const uint2* __restrict__ rec1,
                                              const unsigned short* __restrict__ cnt,
                                              const float* __restrict__ S,
                                              uint4* __restrict__ rec,
                                              int* __restrict__ rstart,
                                              int* __restrict__ plen) {
    __shared__ uint2 lrec[FCAP];
    __shared__ int sbuf[256];
    __shared__ int soff[256];
    __shared__ int lhist[BROWS];
    __shared__ int lsc[BROWS];
    __shared__ int lcur[BROWS];
    __shared__ float s_S[NT_DIM * R_DIM];
    __shared__ int s_nrec;
    int t = threadIdx.x;
    int b = blockIdx.x;
    int pbase = b * CAPR;
    if (t < NT_DIM * R_DIM) s_S[t] = S[t];
    int cv = 0;
    if (t < 256) {
        cv = (t < NBLK1) ? (int)cnt[b * NBLK1 + t] : 0;
        sbuf[t] = cv;
        lhist[t] = 0;
    }
    __syncthreads();
    for (int off = 1; off < 256; off <<= 1) {
        int u = 0;
        if (t < 256 && t >= off) u = sbuf[t - off];
        __syncthreads();
        if (t < 256) sbuf[t] += u;
        __syncthreads();
    }
    if (t < 256) soff[t] = sbuf[t] - cv;
    if (t == 255) s_nrec = sbuf[255];
    __syncthreads();
    int nrec = s_nrec;
    // compact copy: thread t owns cell t
    if (t < NBLK1) {
        const uint2* src = rec1 + (size_t)(b * NBLK1 + t) * CAP;
        int dst = soff[t];
        for (int j = 0; j < cv; ++j) lrec[dst + j] = src[j];
    }
    __syncthreads();
    // row histogram
    for (int i = t; i < nrec; i += 512)
        atomicAdd(&lhist[(lrec[i].x >> 19) & 255], 1);
    __syncthreads();
    int v = 0, vp = 0;
    if (t < 256) { v = lhist[t]; vp = (v + 3) & ~3; lsc[t] = vp; }
    __syncthreads();
    for (int off = 1; off < 256; off <<= 1) {
        int u = 0;
        if (t < 256 && t >= off) u = lsc[t - off];
        __syncthreads();
        if (t < 256) lsc[t] += u;
        __syncthreads();
    }
    if (t < 256) {
        int exclp = lsc[t] - vp;
        int p = b * BROWS + t;
        if (p < N_POST) { rstart[p] = pbase + exclp; plen[p] = vp; }
        lcur[t] = exclp;
    }
    __syncthreads();
    // scatter to final padded row-sorted order, scaling weights by S
    for (int i = t; i < nrec; i += 512) {
        uint2 rc = lrec[i];
        int r = (rc.x >> 19) & 255;
        int pos = atomicAdd(&lcur[r], 1);
        unsigned col = rc.x & 0x7FFF;
        const float* f = &s_S[((rc.x >> 15) & 0xF) * R_DIM];
        float w = __uint_as_float(rc.y);
        uint4 r4;
        r4.x = col << 7;                 // byte offset into fp16 xT
        r4.y = pack2h(w * f[0], w * f[1]);
        r4.z = pack2h(w * f[2], w * f[3]);
        r4.w = pack2h(w * f[4], 0.f);
        rec[pbase + pos] = r4;
    }
    // zero-pad each row to its multiple of 4
    if (t < 256) {
        int exclp = lsc[t] - vp;
        for (int u = v; u < vp; ++u)
            rec[pbase + exclp + u] = make_uint4(0, 0, 0, 0);
    }
}

// FMA of one record into the 10 accumulators (2 t-values x 5 r)
#define FMAREC(Rk, Xk)                                                    \
    do {                                                                  \
        __half2 xh_ = __builtin_bit_cast(__half2, (Xk));                  \
        float xe_ = __half2float(xh_.x), xo_ = __half2float(xh_.y);       \
        float2 w01_ = uph2((Rk).y);                                       \
        float2 w23_ = uph2((Rk).z);                                       \
        float2 w4_  = uph2((Rk).w);                                       \
        a0e = fmaf(xe_, w01_.x, a0e); a0o = fmaf(xo_, w01_.x, a0o);       \
        a1e = fmaf(xe_, w01_.y, a1e); a1o = fmaf(xo_, w01_.y, a1o);       \
        a2e = fmaf(xe_, w23_.x, a2e); a2o = fmaf(xo_, w23_.x, a2o);       \
        a3e = fmaf(xe_, w23_.y, a3e); a3o = fmaf(xo_, w23_.y, a3o);       \
        a4e = fmaf(xe_, w4_.x,  a4e); a4o = fmaf(xo_, w4_.x,  a4o);       \
    } while (0)

// ---- phase2: 16 rows/block; half-wave per row; half2 gather; depth-2 pipeline ----
__global__ __launch_bounds__(256, 4) void k_phase2(
        const __half* __restrict__ xT, const int* __restrict__ rstart,
        const int* __restrict__ plen, const uint4* __restrict__ rec,
        float* __restrict__ out) {
    __shared__ float o_lds[T_DIM * 81];
    const char* xb = (const char*)xT;
    int tid = threadIdx.x;
    int wave = tid >> 6, lane = tid & 63;
    int half = lane >> 5;
    int lane4 = (lane & 31) * 4;          // byte offset of my half2 within a col row
    #pragma unroll
    for (int h = 0; h < 2; ++h) {
        int pa = blockIdx.x * 16 + wave * 4 + h * 2;
        int myrow = pa + half;
        int ih = rstart[myrow];
        int ng = plen[myrow] >> 2;        // my row's group count
        int na = plen[pa], nb = plen[pa + 1];
        int ngmax = __builtin_amdgcn_readfirstlane((na > nb ? na : nb) >> 2);
        const uint4* rp = rec + ih;
        float a0e = 0.f, a0o = 0.f, a1e = 0.f, a1o = 0.f, a2e = 0.f;
        float a2o = 0.f, a3e = 0.f, a3o = 0.f, a4e = 0.f, a4o = 0.f;
        uint4 R0, R1, R2, R3;
        unsigned X0, X1, X2, X3;
        if (0 < ng) {
            R0 = rp[0]; R1 = rp[1]; R2 = rp[2]; R3 = rp[3];
            X0 = *(const unsigned*)(xb + (R0.x + lane4));
            X1 = *(const unsigned*)(xb + (R1.x + lane4));
            X2 = *(const unsigned*)(xb + (R2.x + lane4));
            X3 = *(const unsigned*)(xb + (R3.x + lane4));
        } else {
            R0 = R1 = R2 = R3 = make_uint4(0, 0, 0, 0);
            X0 = X1 = X2 = X3 = 0;
        }
        for (int g = 1; g < ngmax; ++g) {
            uint4 S0, S1, S2, S3;
            unsigned Y0, Y1, Y2, Y3;
            if (g < ng) {
                const uint4* q = rp + (g << 2);
                S0 = q[0]; S1 = q[1]; S2 = q[2]; S3 = q[3];
                Y0 = *(const unsigned*)(xb + (S0.x + lane4));
                Y1 = *(const unsigned*)(xb + (S1.x + lane4));
                Y2 = *(const unsigned*)(xb + (S2.x + lane4));
                Y3 = *(const unsigned*)(xb + (S3.x + lane4));
            } else {
                S0 = S1 = S2 = S3 = make_uint4(0, 0, 0, 0);
                Y0 = Y1 = Y2 = Y3 = 0;
            }
            FMAREC(R0, X0); FMAREC(R1, X1); FMAREC(R2, X2); FMAREC(R3, X3);
            R0 = S0; R1 = S1; R2 = S2; R3 = S3;
            X0 = Y0; X1 = Y1; X2 = Y2; X3 = Y3;
        }
        if (ngmax > 0) {
            FMAREC(R0, X0); FMAREC(R1, X1); FMAREC(R2, X2); FMAREC(R3, X3);
        }
        int rowl = wave * 4 + h * 2 + half;
        int t0 = (lane & 31) * 2;
        float* d0 = &o_lds[t0 * 81 + rowl * 5];
        d0[0] = a0e; d0[1] = a1e; d0[2] = a2e; d0[3] = a3e; d0[4] = a4e;
        float* d1 = &o_lds[(t0 + 1) * 81 + rowl * 5];
        d1[0] = a0o; d1[1] = a1o; d1[2] = a2o; d1[3] = a3o; d1[4] = a4o;
    }
    __syncthreads();
    int base5 = blockIdx.x * 80;
    for (int i2 = tid; i2 < T_DIM * 80; i2 += 256) {
        int t = i2 / 80;
        int j = i2 - t * 80;
        out[(size_t)t * (N_POST * R_DIM) + base5 + j] = o_lds[t * 81 + j];
    }
}

extern "C" void kernel_launch(void* const* d_in, const int* in_sizes, int n_in,
                              void* d_out, int out_size, void* d_ws, size_t ws_size,
                              hipStream_t stream) {
    const float* inp  = (const float*)d_in[0];
    const int2*  idx2 = (const int2*)d_in[1];
    const float* iw   = (const float*)d_in[2];
    const float* S    = (const float*)d_in[3];
    const int*   sid  = (const int*)d_in[4];
    float* out = (float*)d_out;

    char* ws = (char*)d_ws;
    size_t off = 0;
    auto alloc = [&](size_t bytes) -> void* {
        void* p = ws + off;
        off += (bytes + 255) & ~(size_t)255;
        return p;
    };
    __half* xT            = (__half*)alloc((size_t)N_IN * T_DIM * 2);
    unsigned short* cnt   = (unsigned short*)alloc((size_t)NBUCK * NBLK1 * 2);
    int*   rstart         = (int*)alloc((size_t)N_POST * 4);
    int*   plen           = (int*)alloc((size_t)N_POST * 4);
    uint2* rec1           = (uint2*)alloc((size_t)NBUCK * NBLK1 * CAP * 8);
    uint4* rec            = (uint4*)alloc((size_t)NBUCK * CAPR * 16);

    k_trans<<<CTILES, 256, 0, stream>>>(inp, xT);
    k_split<<<NBLK1, 256, 0, stream>>>(idx2, iw, sid, cnt, rec1);
    k_fine<<<NBUCK, 512, 0, stream>>>(rec1, cnt, S, rec, rstart, plen);
    k_phase2<<<N_POST / 16, 256, 0, stream>>>(xT, rstart, plen, rec, out);
}

// Round 13
// 77.220 us; speedup vs baseline: 1.3085x; 1.0180x over previous
//
#include <hip/hip_runtime.h>
#include <hip/hip_fp16.h>

#define N_POST 50000
#define N_IN   17400
#define NNZ_E  1000000
#define T_DIM  64
#define R_DIM  5
#define NT_DIM 10

#define BROWS  256                                  // rows per bucket
#define NBUCK  ((N_POST + BROWS - 1) / BROWS)       // 196
#define EPB    4096                                 // edges per split block
#define NBLK1  ((NNZ_E + EPB - 1) / EPB)            // 245
#define CAP    64                                   // records per (block,bucket) cell
#define FCAP   5632                                 // max records per bucket (mean 5102)
#define CAPR   7168                                 // padded rec stride per bucket
#define CTILES ((N_IN + 63) / 64)                   // 272

static __device__ __forceinline__ unsigned pack2h(float a, float b) {
    __half2 h = __floats2half2_rn(a, b);
    return *reinterpret_cast<unsigned*>(&h);
}

// ---- LDS-tile transpose: x (64 x 17400) -> xT fp16 (17400 x 64), coalesced both sides ----
__global__ __launch_bounds__(256) void k_trans(const float* __restrict__ x,
                                               __half* __restrict__ xT) {
    __shared__ float tile[64][65];
    int c0 = blockIdx.x * 64;
    int tid = threadIdx.x;
    int l = tid & 63, w = tid >> 6;
    #pragma unroll
    for (int i = 0; i < 16; ++i) {
        int t = i * 4 + w;
        int c = c0 + l;
        tile[l][t] = (c < N_IN) ? x[t * N_IN + c] : 0.f;
    }
    __syncthreads();
    #pragma unroll
    for (int i = 0; i < 16; ++i) {
        int cc = i * 4 + w;
        int c = c0 + cc;
        if (c < N_IN) xT[c * 64 + l] = __float2half(tile[cc][l]);
    }
}

// ---- single-pass bucket binning into fixed-capacity cells; ONE LDS atomic/edge ----
// rec1 record: x = col(15b) | sid<<15 (4b) | row_low<<19 (8b) ; y = weight bits
__global__ __launch_bounds__(256) void k_split(const int2* __restrict__ idx2,
                                               const float* __restrict__ iw,
                                               const int* __restrict__ sid,
                                               unsigned short* __restrict__ cnt,
                                               uint2* __restrict__ rec1) {
    __shared__ int lcur[NBUCK];
    int t = threadIdx.x;
    for (int i = t; i < NBUCK; i += 256) lcur[i] = 0;
    __syncthreads();
    int blk = blockIdx.x;
    int base = blk * EPB;
    int n = min(EPB, NNZ_E - base);
    for (int i = t; i < n; i += 256) {
        int2 rc = idx2[base + i];
        unsigned bk = (unsigned)rc.x >> 8;
        int pos = atomicAdd(&lcur[bk], 1);
        unsigned xx = (unsigned)rc.y | ((unsigned)sid[base + i] << 15)
                    | ((unsigned)(rc.x & 255) << 19);
        rec1[(bk * NBLK1 + blk) * CAP + pos] =
            make_uint2(xx, __float_as_uint(iw[base + i]));
    }
    __syncthreads();
    for (int i = t; i < NBUCK; i += 256)
        cnt[i * NBLK1 + blk] = (unsigned short)lcur[i];
}

// ---- per-bucket: compact cells into LDS, row-hist, scan, emit padded fp16 records ----
// rec (uint4): { col<<7, half2(wf0,wf1), half2(wf2,wf3), half2(wf4,0) }
__global__ __launch_bounds__(512) void k_fine(const uint2* __restrict__ rec1,
                                              const unsigned short* __restrict__ cnt,
                                              const float* __restrict__ S,
                                              uint4* __restrict__ rec,
                                              int* __restrict__ rstart,
                                              int* __restrict__ plen) {
    __shared__ uint2 lrec[FCAP];
    __shared__ int sbuf[256];
    __shared__ int soff[256];
    __shared__ int lhist[BROWS];
    __shared__ int lsc[BROWS];
    __shared__ int lcur[BROWS];
    __shared__ float s_S[NT_DIM * R_DIM];
    __shared__ int s_nrec;
    int t = threadIdx.x;
    int b = blockIdx.x;
    int pbase = b * CAPR;
    if (t < NT_DIM * R_DIM) s_S[t] = S[t];
    int cv = 0;
    if (t < 256) {
        cv = (t < NBLK1) ? (int)cnt[b * NBLK1 + t] : 0;
        sbuf[t] = cv;
        lhist[t] = 0;
    }
    __syncthreads();
    for (int off = 1; off < 256; off <<= 1) {
        int u = 0;
        if (t < 256 && t >= off) u = sbuf[t - off];
        __syncthreads();
        if (t < 256) sbuf[t] += u;
        __syncthreads();
    }
    if (t < 256) soff[t] = sbuf[t] - cv;
    if (t == 255) s_nrec = sbuf[255];
    __syncthreads();
    int nrec = s_nrec;
    // compact copy: thread t owns cell t
    if (t < NBLK1) {
        const uint2* src = rec1 + (size_t)(b * NBLK1 + t) * CAP;
        int dst = soff[t];
        for (int j = 0; j < cv; ++j) lrec[dst + j] = src[j];
    }
    __syncthreads();
    // row histogram
    for (int i = t; i < nrec; i += 512)
        atomicAdd(&lhist[(lrec[i].x >> 19) & 255], 1);
    __syncthreads();
    int v = 0, vp = 0;
    if (t < 256) { v = lhist[t]; vp = (v + 3) & ~3; lsc[t] = vp; }
    __syncthreads();
    for (int off = 1; off < 256; off <<= 1) {
        int u = 0;
        if (t < 256 && t >= off) u = lsc[t - off];
        __syncthreads();
        if (t < 256) lsc[t] += u;
        __syncthreads();
    }
    if (t < 256) {
        int exclp = lsc[t] - vp;
        int p = b * BROWS + t;
        if (p < N_POST) { rstart[p] = pbase + exclp; plen[p] = vp; }
        lcur[t] = exclp;
    }
    __syncthreads();
    // scatter to final padded row-sorted order, scaling weights by S
    for (int i = t; i < nrec; i += 512) {
        uint2 rc = lrec[i];
        int r = (rc.x >> 19) & 255;
        int pos = atomicAdd(&lcur[r], 1);
        unsigned col = rc.x & 0x7FFF;
        const float* f = &s_S[((rc.x >> 15) & 0xF) * R_DIM];
        float w = __uint_as_float(rc.y);
        uint4 r4;
        r4.x = col << 7;                 // byte offset into fp16 xT
        r4.y = pack2h(w * f[0], w * f[1]);
        r4.z = pack2h(w * f[2], w * f[3]);
        r4.w = pack2h(w * f[4], 0.f);
        rec[pbase + pos] = r4;
    }
    // zero-pad each row to its multiple of 4
    if (t < 256) {
        int exclp = lsc[t] - vp;
        for (int u = v; u < vp; ++u)
            rec[pbase + exclp + u] = make_uint4(0, 0, 0, 0);
    }
}

// FMA of one record into the 10 accumulators (2 t-values x 5 r) via v_fma_mix_f32:
// fp16 operands consumed directly (internal f32 convert), fp32 accumulate.
// op_sel picks x half (t even/odd) and w half (r index); numerics identical to cvt+fma.
#define FMAREC(Rk, Xk)                                                              \
    do {                                                                            \
        unsigned x_ = (Xk);                                                         \
        unsigned w01_ = (Rk).y, w23_ = (Rk).z, w4_ = (Rk).w;                        \
        asm("v_fma_mix_f32 %0, %1, %2, %0 op_sel:[0,0,0] op_sel_hi:[1,1,0]"         \
            : "+v"(a0e) : "v"(x_), "v"(w01_));                                      \
        asm("v_fma_mix_f32 %0, %1, %2, %0 op_sel:[1,0,0] op_sel_hi:[1,1,0]"         \
            : "+v"(a0o) : "v"(x_), "v"(w01_));                                      \
        asm("v_fma_mix_f32 %0, %1, %2, %0 op_sel:[0,1,0] op_sel_hi:[1,1,0]"         \
            : "+v"(a1e) : "v"(x_), "v"(w01_));                                      \
        asm("v_fma_mix_f32 %0, %1, %2, %0 op_sel:[1,1,0] op_sel_hi:[1,1,0]"         \
            : "+v"(a1o) : "v"(x_), "v"(w01_));                                      \
        asm("v_fma_mix_f32 %0, %1, %2, %0 op_sel:[0,0,0] op_sel_hi:[1,1,0]"         \
            : "+v"(a2e) : "v"(x_), "v"(w23_));                                      \
        asm("v_fma_mix_f32 %0, %1, %2, %0 op_sel:[1,0,0] op_sel_hi:[1,1,0]"         \
            : "+v"(a2o) : "v"(x_), "v"(w23_));                                      \
        asm("v_fma_mix_f32 %0, %1, %2, %0 op_sel:[0,1,0] op_sel_hi:[1,1,0]"         \
            : "+v"(a3e) : "v"(x_), "v"(w23_));                                      \
        asm("v_fma_mix_f32 %0, %1, %2, %0 op_sel:[1,1,0] op_sel_hi:[1,1,0]"         \
            : "+v"(a3o) : "v"(x_), "v"(w23_));                                      \
        asm("v_fma_mix_f32 %0, %1, %2, %0 op_sel:[0,0,0] op_sel_hi:[1,1,0]"         \
            : "+v"(a4e) : "v"(x_), "v"(w4_));                                       \
        asm("v_fma_mix_f32 %0, %1, %2, %0 op_sel:[1,0,0] op_sel_hi:[1,1,0]"         \
            : "+v"(a4o) : "v"(x_), "v"(w4_));                                       \
    } while (0)

// ---- phase2: 16 rows/block; half-wave per row; half2 gather; depth-2 pipeline ----
__global__ __launch_bounds__(256, 4) void k_phase2(
        const __half* __restrict__ xT, const int* __restrict__ rstart,
        const int* __restrict__ plen, const uint4* __restrict__ rec,
        float* __restrict__ out) {
    __shared__ float o_lds[T_DIM * 81];
    const char* xb = (const char*)xT;
    int tid = threadIdx.x;
    int wave = tid >> 6, lane = tid & 63;
    int half = lane >> 5;
    int lane4 = (lane & 31) * 4;          // byte offset of my half2 within a col row
    #pragma unroll
    for (int h = 0; h < 2; ++h) {
        int pa = blockIdx.x * 16 + wave * 4 + h * 2;
        int myrow = pa + half;
        int ih = rstart[myrow];
        int ng = plen[myrow] >> 2;        // my row's group count
        int na = plen[pa], nb = plen[pa + 1];
        int ngmax = __builtin_amdgcn_readfirstlane((na > nb ? na : nb) >> 2);
        const uint4* rp = rec + ih;
        float a0e = 0.f, a0o = 0.f, a1e = 0.f, a1o = 0.f, a2e = 0.f;
        float a2o = 0.f, a3e = 0.f, a3o = 0.f, a4e = 0.f, a4o = 0.f;
        uint4 R0, R1, R2, R3;
        unsigned X0, X1, X2, X3;
        if (0 < ng) {
            R0 = rp[0]; R1 = rp[1]; R2 = rp[2]; R3 = rp[3];
            X0 = *(const unsigned*)(xb + (R0.x + lane4));
            X1 = *(const unsigned*)(xb + (R1.x + lane4));
            X2 = *(const unsigned*)(xb + (R2.x + lane4));
            X3 = *(const unsigned*)(xb + (R3.x + lane4));
        } else {
            R0 = R1 = R2 = R3 = make_uint4(0, 0, 0, 0);
            X0 = X1 = X2 = X3 = 0;
        }
        for (int g = 1; g < ngmax; ++g) {
            uint4 S0, S1, S2, S3;
            unsigned Y0, Y1, Y2, Y3;
            if (g < ng) {
                const uint4* q = rp + (g << 2);
                S0 = q[0]; S1 = q[1]; S2 = q[2]; S3 = q[3];
                Y0 = *(const unsigned*)(xb + (S0.x + lane4));
                Y1 = *(const unsigned*)(xb + (S1.x + lane4));
                Y2 = *(const unsigned*)(xb + (S2.x + lane4));
                Y3 = *(const unsigned*)(xb + (S3.x + lane4));
            } else {
                S0 = S1 = S2 = S3 = make_uint4(0, 0, 0, 0);
                Y0 = Y1 = Y2 = Y3 = 0;
            }
            FMAREC(R0, X0); FMAREC(R1, X1); FMAREC(R2, X2); FMAREC(R3, X3);
            R0 = S0; R1 = S1; R2 = S2; R3 = S3;
            X0 = Y0; X1 = Y1; X2 = Y2; X3 = Y3;
        }
        if (ngmax > 0) {
            FMAREC(R0, X0); FMAREC(R1, X1); FMAREC(R2, X2); FMAREC(R3, X3);
        }
        int rowl = wave * 4 + h * 2 + half;
        int t0 = (lane & 31) * 2;
        float* d0 = &o_lds[t0 * 81 + rowl * 5];
        d0[0] = a0e; d0[1] = a1e; d0[2] = a2e; d0[3] = a3e; d0[4] = a4e;
        float* d1 = &o_lds[(t0 + 1) * 81 + rowl * 5];
        d1[0] = a0o; d1[1] = a1o; d1[2] = a2o; d1[3] = a3o; d1[4] = a4o;
    }
    __syncthreads();
    int base5 = blockIdx.x * 80;
    for (int i2 = tid; i2 < T_DIM * 80; i2 += 256) {
        int t = i2 / 80;
        int j = i2 - t * 80;
        out[(size_t)t * (N_POST * R_DIM) + base5 + j] = o_lds[t * 81 + j];
    }
}

extern "C" void kernel_launch(void* const* d_in, const int* in_sizes, int n_in,
                              void* d_out, int out_size, void* d_ws, size_t ws_size,
                              hipStream_t stream) {
    const float* inp  = (const float*)d_in[0];
    const int2*  idx2 = (const int2*)d_in[1];
    const float* iw   = (const float*)d_in[2];
    const float* S    = (const float*)d_in[3];
    const int*   sid  = (const int*)d_in[4];
    float* out = (float*)d_out;

    char* ws = (char*)d_ws;
    size_t off = 0;
    auto alloc = [&](size_t bytes) -> void* {
        void* p = ws + off;
        off += (bytes + 255) & ~(size_t)255;
        return p;
    };
    __half* xT            = (__half*)alloc((size_t)N_IN * T_DIM * 2);
    unsigned short* cnt   = (unsigned short*)alloc((size_t)NBUCK * NBLK1 * 2);
    int*   rstart         = (int*)alloc((size_t)N_POST * 4);
    int*   plen           = (int*)alloc((size_t)N_POST * 4);
    uint2* rec1           = (uint2*)alloc((size_t)NBUCK * NBLK1 * CAP * 8);
    uint4* rec            = (uint4*)alloc((size_t)NBUCK * CAPR * 16);

    k_trans<<<CTILES, 256, 0, stream>>>(inp, xT);
    k_split<<<NBLK1, 256, 0, stream>>>(idx2, iw, sid, cnt, rec1);
    k_fine<<<NBUCK, 512, 0, stream>>>(rec1, cnt, S, rec, rstart, plen);
    k_phase2<<<N_POST / 16, 256, 0, stream>>>(xT, rstart, plen, rec, out);
}

// Round 14
// 77.150 us; speedup vs baseline: 1.3097x; 1.0009x over previous
//
#include <hip/hip_runtime.h>
#include <hip/hip_fp16.h>

#define N_POST 50000
#define N_IN   17400
#define NNZ_E  1000000
#define T_DIM  64
#define R_DIM  5
#define NT_DIM 10

#define BROWS  256                                  // rows per bucket
#define NBUCK  ((N_POST + BROWS - 1) / BROWS)       // 196
#define EPB    4096                                 // edges per split block
#define NBLK1  ((NNZ_E + EPB - 1) / EPB)            // 245
#define CAP    64                                   // records per (block,bucket) cell
#define FCAP   5632                                 // max records per bucket (mean 5102)
#define CAPR   7168                                 // padded rec stride per bucket
#define CTILES ((N_IN + 63) / 64)                   // 272

static __device__ __forceinline__ unsigned pack2h(float a, float b) {
    __half2 h = __floats2half2_rn(a, b);
    return *reinterpret_cast<unsigned*>(&h);
}

// ---- fused grid: blocks [0,CTILES) transpose x -> xT fp16 (LDS tile, coalesced
//      both sides); blocks [CTILES, CTILES+NBLK1) single-pass bucket binning ----
__global__ __launch_bounds__(256) void k_ts(const float* __restrict__ x,
                                            __half* __restrict__ xT,
                                            const int2* __restrict__ idx2,
                                            const float* __restrict__ iw,
                                            const int* __restrict__ sid,
                                            unsigned short* __restrict__ cnt,
                                            uint2* __restrict__ rec1) {
    __shared__ float tile[64][65];                  // also covers split's 1.6KB needs
    int bb = blockIdx.x;
    int tid = threadIdx.x;
    if (bb < CTILES) {
        int c0 = bb * 64;
        int l = tid & 63, w = tid >> 6;
        #pragma unroll
        for (int i = 0; i < 16; ++i) {
            int t = i * 4 + w;
            int c = c0 + l;
            tile[l][t] = (c < N_IN) ? x[t * N_IN + c] : 0.f;
        }
        __syncthreads();
        #pragma unroll
        for (int i = 0; i < 16; ++i) {
            int cc = i * 4 + w;
            int c = c0 + cc;
            if (c < N_IN) xT[c * 64 + l] = __float2half(tile[cc][l]);
        }
        return;
    }
    int* lcur = (int*)&tile[0][0];
    for (int i = tid; i < NBUCK; i += 256) lcur[i] = 0;
    __syncthreads();
    int blk = bb - CTILES;
    int base = blk * EPB;
    int n = min(EPB, NNZ_E - base);
    for (int i = tid; i < n; i += 256) {
        int2 rc = idx2[base + i];
        unsigned bk = (unsigned)rc.x >> 8;
        int pos = atomicAdd(&lcur[bk], 1);
        unsigned xx = (unsigned)rc.y | ((unsigned)sid[base + i] << 15)
                    | ((unsigned)(rc.x & 255) << 19);
        rec1[(bk * NBLK1 + blk) * CAP + pos] =
            make_uint2(xx, __float_as_uint(iw[base + i]));
    }
    __syncthreads();
    for (int i = tid; i < NBUCK; i += 256)
        cnt[i * NBLK1 + blk] = (unsigned short)lcur[i];
}

// ---- per-bucket: parallel slot-compact cells into LDS, row-hist, scan,
//      emit padded fp16 records { col<<7, h2(wf0,wf1), h2(wf2,wf3), h2(wf4,0) } ----
__global__ __launch_bounds__(512) void k_fine(const uint2* __restrict__ rec1,
                                              const unsigned short* __restrict__ cnt,
                                              const float* __restrict__ S,
                                              uint4* __restrict__ rec,
                                              int* __restrict__ rstart,
                                              int* __restrict__ plen) {
    __shared__ uint2 lrec[FCAP];
    __shared__ int scnt[256];
    __shared__ int soff[256];
    __shared__ int lhist[BROWS];
    __shared__ int lsc[BROWS];
    __shared__ int lcur[BROWS];
    __shared__ float s_S[NT_DIM * R_DIM];
    int t = threadIdx.x;
    int b = blockIdx.x;
    int pbase = b * CAPR;
    if (t < NT_DIM * R_DIM) s_S[t] = S[t];
    int cv = 0;
    if (t < 256) {
        cv = (t < NBLK1) ? (int)cnt[b * NBLK1 + t] : 0;
        scnt[t] = cv;
        soff[t] = cv;
        lhist[t] = 0;
    }
    __syncthreads();
    // scan cell counts -> cell offsets
    for (int off = 1; off < 256; off <<= 1) {
        int u = 0;
        if (t < 256 && t >= off) u = soff[t - off];
        __syncthreads();
        if (t < 256) soff[t] += u;
        __syncthreads();
    }
    if (t < 256) soff[t] -= cv;                    // exclusive
    __syncthreads();
    // parallel slot-based compaction: all 512 threads, coalesced
    const uint2* srcb = rec1 + (size_t)b * NBLK1 * CAP;
    for (int slot = t; slot < NBLK1 * CAP; slot += 512) {
        int cell = slot >> 6;
        int j = slot & 63;
        if (j < scnt[cell]) lrec[soff[cell] + j] = srcb[slot];
    }
    int nrec = soff[255] + scnt[255];
    __syncthreads();
    // row histogram
    for (int i = t; i < nrec; i += 512)
        atomicAdd(&lhist[(lrec[i].x >> 19) & 255], 1);
    __syncthreads();
    int v = 0, vp = 0;
    if (t < 256) { v = lhist[t]; vp = (v + 3) & ~3; lsc[t] = vp; }
    __syncthreads();
    for (int off = 1; off < 256; off <<= 1) {
        int u = 0;
        if (t < 256 && t >= off) u = lsc[t - off];
        __syncthreads();
        if (t < 256) lsc[t] += u;
        __syncthreads();
    }
    if (t < 256) {
        int exclp = lsc[t] - vp;
        int p = b * BROWS + t;
        if (p < N_POST) { rstart[p] = pbase + exclp; plen[p] = vp; }
        lcur[t] = exclp;
    }
    __syncthreads();
    // scatter to final padded row-sorted order, scaling weights by S
    for (int i = t; i < nrec; i += 512) {
        uint2 rc = lrec[i];
        int r = (rc.x >> 19) & 255;
        int pos = atomicAdd(&lcur[r], 1);
        unsigned col = rc.x & 0x7FFF;
        const float* f = &s_S[((rc.x >> 15) & 0xF) * R_DIM];
        float w = __uint_as_float(rc.y);
        uint4 r4;
        r4.x = col << 7;                 // byte offset into fp16 xT
        r4.y = pack2h(w * f[0], w * f[1]);
        r4.z = pack2h(w * f[2], w * f[3]);
        r4.w = pack2h(w * f[4], 0.f);
        rec[pbase + pos] = r4;
    }
    // zero-pad each row to its multiple of 4
    if (t < 256) {
        int exclp = lsc[t] - vp;
        for (int u = v; u < vp; ++u)
            rec[pbase + exclp + u] = make_uint4(0, 0, 0, 0);
    }
}

// FMA of one record into the 10 accumulators (2 t-values x 5 r) via v_fma_mix_f32
#define FMAREC(Rk, Xk)                                                              \
    do {                                                                            \
        unsigned x_ = (Xk);                                                         \
        unsigned w01_ = (Rk).y, w23_ = (Rk).z, w4_ = (Rk).w;                        \
        asm("v_fma_mix_f32 %0, %1, %2, %0 op_sel:[0,0,0] op_sel_hi:[1,1,0]"         \
            : "+v"(a0e) : "v"(x_), "v"(w01_));                                      \
        asm("v_fma_mix_f32 %0, %1, %2, %0 op_sel:[1,0,0] op_sel_hi:[1,1,0]"         \
            : "+v"(a0o) : "v"(x_), "v"(w01_));                                      \
        asm("v_fma_mix_f32 %0, %1, %2, %0 op_sel:[0,1,0] op_sel_hi:[1,1,0]"         \
            : "+v"(a1e) : "v"(x_), "v"(w01_));                                      \
        asm("v_fma_mix_f32 %0, %1, %2, %0 op_sel:[1,1,0] op_sel_hi:[1,1,0]"         \
            : "+v"(a1o) : "v"(x_), "v"(w01_));                                      \
        asm("v_fma_mix_f32 %0, %1, %2, %0 op_sel:[0,0,0] op_sel_hi:[1,1,0]"         \
            : "+v"(a2e) : "v"(x_), "v"(w23_));                                      \
        asm("v_fma_mix_f32 %0, %1, %2, %0 op_sel:[1,0,0] op_sel_hi:[1,1,0]"         \
            : "+v"(a2o) : "v"(x_), "v"(w23_));                                      \
        asm("v_fma_mix_f32 %0, %1, %2, %0 op_sel:[0,1,0] op_sel_hi:[1,1,0]"         \
            : "+v"(a3e) : "v"(x_), "v"(w23_));                                      \
        asm("v_fma_mix_f32 %0, %1, %2, %0 op_sel:[1,1,0] op_sel_hi:[1,1,0]"         \
            : "+v"(a3o) : "v"(x_), "v"(w23_));                                      \
        asm("v_fma_mix_f32 %0, %1, %2, %0 op_sel:[0,0,0] op_sel_hi:[1,1,0]"         \
            : "+v"(a4e) : "v"(x_), "v"(w4_));                                       \
        asm("v_fma_mix_f32 %0, %1, %2, %0 op_sel:[1,0,0] op_sel_hi:[1,1,0]"         \
            : "+v"(a4o) : "v"(x_), "v"(w4_));                                       \
    } while (0)

// ---- phase2: 16 rows/block; half-wave per row; half2 gather; depth-2 pipeline ----
__global__ __launch_bounds__(256, 4) void k_phase2(
        const __half* __restrict__ xT, const int* __restrict__ rstart,
        const int* __restrict__ plen, const uint4* __restrict__ rec,
        float* __restrict__ out) {
    __shared__ float o_lds[T_DIM * 81];
    const char* xb = (const char*)xT;
    int tid = threadIdx.x;
    int wave = tid >> 6, lane = tid & 63;
    int half = lane >> 5;
    int lane4 = (lane & 31) * 4;          // byte offset of my half2 within a col row
    #pragma unroll
    for (int h = 0; h < 2; ++h) {
        int pa = blockIdx.x * 16 + wave * 4 + h * 2;
        int myrow = pa + half;
        int ih = rstart[myrow];
        int ng = plen[myrow] >> 2;        // my row's group count
        int na = plen[pa], nb = plen[pa + 1];
        int ngmax = __builtin_amdgcn_readfirstlane((na > nb ? na : nb) >> 2);
        const uint4* rp = rec + ih;
        float a0e = 0.f, a0o = 0.f, a1e = 0.f, a1o = 0.f, a2e = 0.f;
        float a2o = 0.f, a3e = 0.f, a3o = 0.f, a4e = 0.f, a4o = 0.f;
        uint4 R0, R1, R2, R3;
        unsigned X0, X1, X2, X3;
        if (0 < ng) {
            R0 = rp[0]; R1 = rp[1]; R2 = rp[2]; R3 = rp[3];
            X0 = *(const unsigned*)(xb + (R0.x + lane4));
            X1 = *(const unsigned*)(xb + (R1.x + lane4));
            X2 = *(const unsigned*)(xb + (R2.x + lane4));
            X3 = *(const unsigned*)(xb + (R3.x + lane4));
        } else {
            R0 = R1 = R2 = R3 = make_uint4(0, 0, 0, 0);
            X0 = X1 = X2 = X3 = 0;
        }
        for (int g = 1; g < ngmax; ++g) {
            uint4 S0, S1, S2, S3;
            unsigned Y0, Y1, Y2, Y3;
            if (g < ng) {
                const uint4* q = rp + (g << 2);
                S0 = q[0]; S1 = q[1]; S2 = q[2]; S3 = q[3];
                Y0 = *(const unsigned*)(xb + (S0.x + lane4));
                Y1 = *(const unsigned*)(xb + (S1.x + lane4));
                Y2 = *(const unsigned*)(xb + (S2.x + lane4));
                Y3 = *(const unsigned*)(xb + (S3.x + lane4));
            } else {
                S0 = S1 = S2 = S3 = make_uint4(0, 0, 0, 0);
                Y0 = Y1 = Y2 = Y3 = 0;
            }
            FMAREC(R0, X0); FMAREC(R1, X1); FMAREC(R2, X2); FMAREC(R3, X3);
            R0 = S0; R1 = S1; R2 = S2; R3 = S3;
            X0 = Y0; X1 = Y1; X2 = Y2; X3 = Y3;
        }
        if (ngmax > 0) {
            FMAREC(R0, X0); FMAREC(R1, X1); FMAREC(R2, X2); FMAREC(R3, X3);
        }
        int rowl = wave * 4 + h * 2 + half;
        int t0 = (lane & 31) * 2;
        float* d0 = &o_lds[t0 * 81 + rowl * 5];
        d0[0] = a0e; d0[1] = a1e; d0[2] = a2e; d0[3] = a3e; d0[4] = a4e;
        float* d1 = &o_lds[(t0 + 1) * 81 + rowl * 5];
        d1[0] = a0o; d1[1] = a1o; d1[2] = a2o; d1[3] = a3o; d1[4] = a4o;
    }
    __syncthreads();
    int base5 = blockIdx.x * 80;
    for (int i2 = tid; i2 < T_DIM * 80; i2 += 256) {
        int t = i2 / 80;
        int j = i2 - t * 80;
        out[(size_t)t * (N_POST * R_DIM) + base5 + j] = o_lds[t * 81 + j];
    }
}

extern "C" void kernel_launch(void* const* d_in, const int* in_sizes, int n_in,
                              void* d_out, int out_size, void* d_ws, size_t ws_size,
                              hipStream_t stream) {
    const float* inp  = (const float*)d_in[0];
    const int2*  idx2 = (const int2*)d_in[1];
    const float* iw   = (const float*)d_in[2];
    const float* S    = (const float*)d_in[3];
    const int*   sid  = (const int*)d_in[4];
    float* out = (float*)d_out;

    char* ws = (char*)d_ws;
    size_t off = 0;
    auto alloc = [&](size_t bytes) -> void* {
        void* p = ws + off;
        off += (bytes + 255) & ~(size_t)255;
        return p;
    };
    __half* xT            = (__half*)alloc((size_t)N_IN * T_DIM * 2);
    unsigned short* cnt   = (unsigned short*)alloc((size_t)NBUCK * NBLK1 * 2);
    int*   rstart         = (int*)alloc((size_t)N_POST * 4);
    int*   plen           = (int*)alloc((size_t)N_POST * 4);
    uint2* rec1           = (uint2*)alloc((size_t)NBUCK * NBLK1 * CAP * 8);
    uint4* rec            = (uint4*)alloc((size_t)NBUCK * CAPR * 16);

    k_ts<<<CTILES + NBLK1, 256, 0, stream>>>(inp, xT, idx2, iw, sid, cnt, rec1);
    k_fine<<<NBUCK, 512, 0, stream>>>(rec1, cnt, S, rec, rstart, plen);
    k_phase2<<<N_POST / 16, 256, 0, stream>>>(xT, rstart, plen, rec, out);
}